// Round 7
// baseline (150.166 us; speedup 1.0000x reference)
//
#include <hip/hip_runtime.h>

// Problem constants (fixed by the reference)
#define B_   64
#define S_   512
#define P_   300
#define K_   50
#define MPAD 64      // label dim padded to 64 for MFMA M
#define NS   48      // staged s rows per block: 32 + 2*8 halo (3 MFMA N-tiles)
#define SCH  32      // central s columns per block
#define LDB  1232    // staged row stride in BYTES (308 f32; 308%32=20 -> balanced banks)
#define LDM  67      // transposed G-tile stride in floats (odd; spreads banks)

typedef short short8v __attribute__((ext_vector_type(8)));
typedef float float4v __attribute__((ext_vector_type(4)));

__device__ __forceinline__ float bf2f(short h) {
  return __builtin_bit_cast(float, ((unsigned)(unsigned short)h) << 16);
}
__device__ __forceinline__ short f2bf(float f) {
  unsigned u = __builtin_bit_cast(unsigned, f);
  u = (u + 0x7FFFu + ((u >> 16) & 1u)) >> 16;  // RNE
  return (short)u;
}
// packed f32x2 -> bf16x2 (RNE), gfx950 hw instr (no builtin; guide T12)
__device__ __forceinline__ unsigned cvtpk(float lo, float hi) {
  unsigned r;
  asm("v_cvt_pk_bf16_f32 %0, %1, %2" : "=v"(r) : "v"(lo), "v"(hi));
  return r;
}
// async global->LDS DMA, 16B/lane; lds dest = uniform base + lane*16 (HW rule)
__device__ __forceinline__ void dma16(const float* g, void* l) {
  __builtin_amdgcn_global_load_lds(
      (const __attribute__((address_space(1))) void*)g,
      (__attribute__((address_space(3))) void*)l, 16, 0, 0);
}

// ---------------------------------------------------------------------------
// K1: normalize C -> l_hat, pad {l_hat, W2} to 64x320 bf16 (zeros), and pack
// into MFMA A-fragment order so K2's A loads are coalesced 16B/lane.
// apack layout: [(mat*4 + mtile)*10 + kstep][lane][8 bf16]
// ---------------------------------------------------------------------------
__global__ __launch_bounds__(64) void k1_prep(const float* __restrict__ C,
                                              const float* __restrict__ W2,
                                              short* __restrict__ apack) {
  int bid = blockIdx.x;
  int mat = bid / 40;
  int rem = bid - mat * 40;
  int mt  = rem / 10;
  int ks  = rem - mt * 10;
  int lane = threadIdx.x;
  __shared__ float invn[16];
  if (mat == 0) {
    int rl = lane >> 2, q = lane & 3;
    int m = mt * 16 + rl;
    float ss = 0.f;
    if (m < K_) {
      for (int p = q; p < P_; p += 4) { float v = C[m * P_ + p]; ss += v * v; }
    }
    ss += __shfl_xor(ss, 1);
    ss += __shfl_xor(ss, 2);
    if (q == 0) invn[rl] = 1.f / (sqrtf(ss) + 0.001f);
  }
  __syncthreads();
  int ml = lane & 15, quad = lane >> 4;
  int m = mt * 16 + ml;
  const float* src = (mat == 0) ? C : W2;
  short8v v8;
  #pragma unroll
  for (int j = 0; j < 8; ++j) {
    int k = ks * 32 + quad * 8 + j;
    float v = 0.f;
    if (m < K_ && k < P_) {
      v = src[m * P_ + k];
      if (mat == 0) v *= invn[ml];
    }
    v8[j] = f2bf(v);
  }
  *(short8v*)(apack + (size_t)(((mat * 4 + mt) * 10 + ks) * 512 + lane * 8)) = v8;
}

// ---------------------------------------------------------------------------
// K2 (fused GEMM + conv), DMA-staged gather:
//   grid 1024 x 256: block = (b, 32-s chunk) with +-8 s halo (48 staged rows).
//   Stage: per row, TWO full-wave global_load_lds (bytes 0..1024 and
//   176..1200, overlap benign) -> f32 rows land in LDS with NO VGPR payload
//   and maximal outstanding requests (compiler cannot serialize a DMA).
//   Each wave then waits its own vmcnt(0) and converts ITS rows in place to
//   bf16 (cvt_pk, norm computed in the same pass). Barrier only before MFMA.
//   LDS 59 KB -> 2 blocks/CU; queue depth, not occupancy, hides HBM latency.
// ---------------------------------------------------------------------------
__global__ __launch_bounds__(256, 2) void k2_gemm(const int* __restrict__ idx,
                                                  const float* __restrict__ emb,
                                                  const short* __restrict__ apack,
                                                  short* __restrict__ Yt,
                                                  const float* __restrict__ conv_w,
                                                  const float* __restrict__ conv_b,
                                                  float* __restrict__ mbuf) {
  __shared__ __align__(16) char smem_raw[NS * LDB];  // 59136 B
  __shared__ float scale_s[NS];
  __shared__ float mpart[8][SCH];
  float (*gst)[LDM] = (float(*)[LDM])smem_raw;  // recycled post-MFMA: [48][67]

  int bid = blockIdx.x;
  int b = bid >> 4, s0 = (bid & 15) * SCH;
  int tid = threadIdx.x;
  int lane = tid & 63;
  int wu = __builtin_amdgcn_readfirstlane(tid >> 6);  // wave id as SGPR

  // --- scalar row indices (uniform addresses -> s_load) ---
  int rows[12];
  #pragma unroll
  for (int r = 0; r < 12; ++r) {
    int sg = s0 - 8 + wu * 12 + r;
    int sgc = sg < 0 ? 0 : (sg >= S_ ? S_ - 1 : sg);
    rows[r] = idx[b * S_ + sgc];
  }

  // --- issue all DMAs back-to-back (24 per wave, all outstanding) ---
  #pragma unroll
  for (int r = 0; r < 12; ++r) {
    int ls = wu * 12 + r;
    int sg = s0 - 8 + ls;
    if (sg >= 0 && sg < S_) {                       // wave-uniform branch
      const float* src = emb + (size_t)rows[r] * P_;
      char* dst = smem_raw + ls * LDB;
      dma16(src + 4 * lane, dst);                   // bytes 0..1024
      dma16(src + 44 + 4 * lane, dst + 176);        // bytes 176..1200
    }
  }

  // --- A-fragment prefetch to regs (L2-hot; (256,2) cap -> no spill) ---
  const short8v* a1p = (const short8v*)(apack) + (size_t)((0 * 4 + wu) * 10) * 64 + lane;
  const short8v* a2p = (const short8v*)(apack) + (size_t)((1 * 4 + wu) * 10) * 64 + lane;
  short8v a1f[10], a2f[10];
  #pragma unroll
  for (int ks = 0; ks < 10; ++ks) { a1f[ks] = a1p[ks * 64]; a2f[ks] = a2p[ks * 64]; }

  // wait own DMAs (per-wave; no block barrier needed for own-row convert)
  asm volatile("s_waitcnt vmcnt(0)" ::: "memory");

  // --- in-place f32 -> bf16 convert + norm, wave-private rows ---
  // reads (16B/lane) all issue before writes (8B/lane); same-wave LDS ops are
  // ordered, and compiler must keep order (may-alias through smem_raw).
  #pragma unroll
  for (int r = 0; r < 12; ++r) {
    int ls = wu * 12 + r;
    int sg = s0 - 8 + ls;
    char* rowp = smem_raw + ls * LDB;
    float ss = 0.f;
    if (sg >= 0 && sg < S_) {
      float4 va = *(const float4*)(rowp + 16 * lane);          // cols 4L..4L+4
      float4 vb = {0.f, 0.f, 0.f, 0.f};
      if (lane < 11) vb = *(const float4*)(rowp + 1024 + 16 * lane);  // 256..300
      ss = va.x * va.x + va.y * va.y + va.z * va.z + va.w * va.w +
           vb.x * vb.x + vb.y * vb.y + vb.z * vb.z + vb.w * vb.w;
      unsigned u0 = cvtpk(va.x, va.y), u1 = cvtpk(va.z, va.w);
      *(uint2*)(rowp + 8 * lane) = make_uint2(u0, u1);         // bf16 cols 4L..
      if (lane < 11) {
        unsigned u2 = cvtpk(vb.x, vb.y), u3 = cvtpk(vb.z, vb.w);
        *(uint2*)(rowp + 512 + 8 * lane) = make_uint2(u2, u3); // cols 256..300
      }
      if (lane < 5) *(uint2*)(rowp + 600 + 8 * lane) = make_uint2(0u, 0u); // 300..320
    } else {  // OOB halo row: zero bf16 cols 0..320 (conv pad semantics)
      *(uint2*)(rowp + 8 * lane) = make_uint2(0u, 0u);
      if (lane < 16) *(uint2*)(rowp + 512 + 8 * lane) = make_uint2(0u, 0u);
    }
    #pragma unroll
    for (int off = 32; off > 0; off >>= 1) ss += __shfl_xor(ss, off);
    if (lane == 0) scale_s[ls] = 1.f / (sqrtf(ss) + 0.001f);
  }
  __syncthreads();

  // --- dual GEMM: bf16 rows at byte ls*LDB + k*2. G: 3 tiles, Y: central 2.
  float4v accG[3] = {};
  float4v accY[2] = {};
  int ml = lane & 15, quad = lane >> 4;
  #pragma unroll
  for (int ks = 0; ks < 10; ++ks) {
    int kb = (ks * 32 + quad * 8) * 2;   // byte offset of 8 bf16
    #pragma unroll
    for (int nt = 0; nt < 3; ++nt) {
      short8v bg = *(const short8v*)(smem_raw + (nt * 16 + ml) * LDB + kb);
      accG[nt] = __builtin_amdgcn_mfma_f32_16x16x32_bf16(a1f[ks], bg, accG[nt], 0, 0, 0);
    }
    #pragma unroll
    for (int nt = 0; nt < 2; ++nt) {
      short8v by = *(const short8v*)(smem_raw + (8 + nt * 16 + ml) * LDB + kb);
      accY[nt] = __builtin_amdgcn_mfma_f32_16x16x32_bf16(a2f[ks], by, accY[nt], 0, 0, 0);
    }
  }

  // --- Yt epilogue. C/D: col = lane&15 (s), row = quad*4+reg (m)
  #pragma unroll
  for (int nt = 0; nt < 2; ++nt) {
    int sg = s0 + nt * 16 + ml;
    #pragma unroll
    for (int reg = 0; reg < 4; ++reg) {
      int m = wu * 16 + quad * 4 + reg;
      if (m < K_) Yt[(size_t)(b * MPAD + m) * S_ + sg] = f2bf(accY[nt][reg]);
    }
  }

  // conv weights (uniform -> scalar loads)
  float wvv[11];
  #pragma unroll
  for (int t = 0; t < 11; ++t) wvv[t] = conv_w[t];
  float cb = conv_b[0];

  __syncthreads();  // all MFMA LDS reads done -> safe to recycle as gst

  // --- scaled G tile -> LDS transposed: gst[scol][m] ---
  #pragma unroll
  for (int nt = 0; nt < 3; ++nt) {
    int scol = nt * 16 + ml;
    float sc = scale_s[scol];
    #pragma unroll
    for (int reg = 0; reg < 4; ++reg) {
      int m = wu * 16 + quad * 4 + reg;
      gst[scol][m] = accG[nt][reg] * sc;
    }
  }
  __syncthreads();

  // --- conv + relu + max over k. thread = (s = tid&31, k-group = tid>>5). ---
  // center s staged index = sl+8; taps at staged cols sl+3 .. sl+13 (max 44 < 48).
  int sl = tid & 31, kg = tid >> 5;
  float part = 0.f;  // relu >= 0, safe identity
  for (int k = kg; k < K_; k += 8) {
    float acc = cb;
    #pragma unroll
    for (int t = 0; t < 11; ++t) acc += wvv[t] * gst[sl + 3 + t][k];
    part = fmaxf(part, fmaxf(acc, 0.f));
  }
  mpart[kg][sl] = part;
  __syncthreads();
  if (tid < SCH) {
    float m0 = mpart[0][tid];
    #pragma unroll
    for (int i = 1; i < 8; ++i) m0 = fmaxf(m0, mpart[i][tid]);
    mbuf[b * S_ + s0 + tid] = m0;
  }
}

// ---------------------------------------------------------------------------
// K3: 4 blocks per b (grid 256, 512 threads). Each block recomputes the
// softmax over mbuf[b,:] (2 KB, cheap) and pools its k-subset of Yt.
// ---------------------------------------------------------------------------
__global__ __launch_bounds__(512) void k3_pool(const float* __restrict__ mbuf,
                                               const short* __restrict__ Yt,
                                               const float* __restrict__ b2,
                                               float* __restrict__ out) {
  __shared__ float beta[S_];
  __shared__ float red[8];
  int b = blockIdx.x >> 2, part = blockIdx.x & 3;
  int tid = threadIdx.x;
  int lane = tid & 63, wv = tid >> 6;

  float mx = mbuf[b * S_ + tid];

  // block softmax over s (512 threads)
  float r = mx;
  #pragma unroll
  for (int off = 32; off > 0; off >>= 1) r = fmaxf(r, __shfl_xor(r, off));
  if (lane == 0) red[wv] = r;
  __syncthreads();
  float bm = red[0];
  #pragma unroll
  for (int i = 1; i < 8; ++i) bm = fmaxf(bm, red[i]);
  float e = __expf(mx - bm);
  r = e;
  #pragma unroll
  for (int off = 32; off > 0; off >>= 1) r += __shfl_xor(r, off);
  __syncthreads();               // everyone done reading red (max) before rewrite
  if (lane == 0) red[wv] = r;
  __syncthreads();
  float sum = 0.f;
  #pragma unroll
  for (int i = 0; i < 8; ++i) sum += red[i];
  beta[tid] = e / (sum * (float)S_);   // fold 1/S of jnp.mean into beta
  __syncthreads();

  // out[b,k] = sum_s beta[s]*Yt[b,k,s] + b2[k]; this block covers k≡part (mod 4)
  const float4* bp = (const float4*)&beta[lane * 8];
  float4 b0 = bp[0], b1 = bp[1];
  for (int k = part + 4 * wv; k < K_; k += 32) {
    short8v y = *(const short8v*)(Yt + (((size_t)(b * MPAD + k)) << 9) + lane * 8);
    float acc = b0.x * bf2f(y[0]) + b0.y * bf2f(y[1]) +
                b0.z * bf2f(y[2]) + b0.w * bf2f(y[3]) +
                b1.x * bf2f(y[4]) + b1.y * bf2f(y[5]) +
                b1.z * bf2f(y[6]) + b1.w * bf2f(y[7]);
    #pragma unroll
    for (int off = 32; off > 0; off >>= 1) acc += __shfl_xor(acc, off);
    if (lane == 0) out[b * K_ + k] = acc + b2[k];
  }
}

// ---------------------------------------------------------------------------
extern "C" void kernel_launch(void* const* d_in, const int* in_sizes, int n_in,
                              void* d_out, int out_size, void* d_ws, size_t ws_size,
                              hipStream_t stream) {
  const int*   idx    = (const int*)  d_in[0];
  const float* emb    = (const float*)d_in[1];
  const float* C      = (const float*)d_in[2];
  const float* conv_w = (const float*)d_in[3];
  const float* conv_b = (const float*)d_in[4];
  const float* W2     = (const float*)d_in[5];
  const float* b2     = (const float*)d_in[6];
  float* out = (float*)d_out;

  char* ws = (char*)d_ws;
  // ws layout (bytes): apack 81920 | Yt bf16 4 MiB | mbuf f32 128 KiB
  short* apack = (short*)(ws);
  short* Yt    = (short*)(ws + 81920);
  float* mbuf  = (float*)(ws + 81920 + 4194304);

  hipLaunchKernelGGL(k1_prep, dim3(80),   dim3(64),  0, stream, C, W2, apack);
  hipLaunchKernelGGL(k2_gemm, dim3(1024), dim3(256), 0, stream,
                     idx, emb, apack, Yt, conv_w, conv_b, mbuf);
  hipLaunchKernelGGL(k3_pool, dim3(256),  dim3(512), 0, stream, mbuf, Yt, b2, out);
}

// Round 8
// 139.206 us; speedup vs baseline: 1.0787x; 1.0787x over previous
//
#include <hip/hip_runtime.h>

// Problem constants (fixed by the reference)
#define B_   64
#define S_   512
#define P_   300
#define K_   50
#define MPAD 64      // label dim padded to 64 for MFMA M
#define LDX  344     // x_tile row stride in bf16 elems (16B-aligned rows, bank-balanced)
#define NS   48      // staged s rows per block: 32 + 2*8 halo (3 MFMA N-tiles)
#define SCH  32      // central s columns per block
#define LDM  67      // transposed G-tile stride in floats (odd; spreads banks)

typedef short short8v __attribute__((ext_vector_type(8)));
typedef float float4v __attribute__((ext_vector_type(4)));

__device__ __forceinline__ short f2bf(float f) {
  unsigned u = __builtin_bit_cast(unsigned, f);
  u = (u + 0x7FFFu + ((u >> 16) & 1u)) >> 16;  // RNE
  return (short)u;
}
__device__ __forceinline__ float bf2f(short h) {
  return __builtin_bit_cast(float, ((unsigned)(unsigned short)h) << 16);
}
// packed f32x2 -> bf16x2 (RNE), gfx950 hw instr
__device__ __forceinline__ unsigned cvtpk(float lo, float hi) {
  unsigned r;
  asm("v_cvt_pk_bf16_f32 %0, %1, %2" : "=v"(r) : "v"(lo), "v"(hi));
  return r;
}

// ---------------------------------------------------------------------------
// K1: normalize C -> l_hat, pad {l_hat, W2} to 64x320 bf16 (zeros), and pack
// into MFMA A-fragment order so K2's A loads are coalesced 16B/lane.
// apack layout: [(mat*4 + mtile)*10 + kstep][lane][8 bf16]
// ---------------------------------------------------------------------------
__global__ __launch_bounds__(64) void k1_prep(const float* __restrict__ C,
                                              const float* __restrict__ W2,
                                              short* __restrict__ apack) {
  int bid = blockIdx.x;
  int mat = bid / 40;
  int rem = bid - mat * 40;
  int mt  = rem / 10;
  int ks  = rem - mt * 10;
  int lane = threadIdx.x;
  __shared__ float invn[16];
  if (mat == 0) {
    int rl = lane >> 2, q = lane & 3;
    int m = mt * 16 + rl;
    float ss = 0.f;
    if (m < K_) {
      for (int p = q; p < P_; p += 4) { float v = C[m * P_ + p]; ss += v * v; }
    }
    ss += __shfl_xor(ss, 1);
    ss += __shfl_xor(ss, 2);
    if (q == 0) invn[rl] = 1.f / (sqrtf(ss) + 0.001f);
  }
  __syncthreads();
  int ml = lane & 15, quad = lane >> 4;
  int m = mt * 16 + ml;
  const float* src = (mat == 0) ? C : W2;
  short8v v8;
  #pragma unroll
  for (int j = 0; j < 8; ++j) {
    int k = ks * 32 + quad * 8 + j;
    float v = 0.f;
    if (m < K_ && k < P_) {
      v = src[m * P_ + k];
      if (mat == 0) v *= invn[ml];
    }
    v8[j] = f2bf(v);
  }
  *(short8v*)(apack + (size_t)(((mat * 4 + mt) * 10 + ks) * 512 + lane * 8)) = v8;
}

// ---------------------------------------------------------------------------
// K2 (fused GEMM + conv), r6 structure + MLP-forced gather:
//   grid 1024 x 256: block = (b, 32-s chunk) with +-8 s halo (48 staged rows).
//   LDS 34.3 KB -> 4 blocks/CU; launch_bounds(256,4), no A-prefetch arrays.
//   Gather fix (r5's VGPR=52 showed the compiler serialized prior batches):
//   each row = TWO FULL-WAVE uniform float4 loads (f32 cols 4L.. and 44+4L..,
//   lane 63 ends at col 299 exactly -> no divergence in the load stream);
//   6-row batches (12 loads, 48 VGPR) fenced with sched_barrier(0) so loads
//   cannot be sunk into their uses. Convert phase does lane-predication.
// ---------------------------------------------------------------------------
__global__ __launch_bounds__(256, 4) void k2_gemm(const int* __restrict__ idx,
                                                  const float* __restrict__ emb,
                                                  const short* __restrict__ apack,
                                                  short* __restrict__ Yt,
                                                  const float* __restrict__ conv_w,
                                                  const float* __restrict__ conv_b,
                                                  float* __restrict__ mbuf) {
  __shared__ __align__(16) char smem_raw[NS * LDX * 2];  // 33024 B
  __shared__ float scale_s[NS];
  __shared__ float mpart[8][SCH];
  short (*xt)[LDX] = (short(*)[LDX])smem_raw;
  float (*gst)[LDM] = (float(*)[LDM])smem_raw;  // recycled: [48 s][67] transposed G

  int bid = blockIdx.x;
  int b = bid >> 4, s0 = (bid & 15) * SCH;
  int tid = threadIdx.x;
  int lane = tid & 63;
  int wu = __builtin_amdgcn_readfirstlane(tid >> 6);  // wave id as SGPR

  // --- scalar row indices (uniform addresses, all independent; clamped) ---
  int rows[12];
  #pragma unroll
  for (int r = 0; r < 12; ++r) {
    int sg = s0 - 8 + wu * 12 + r;
    int sgc = sg < 0 ? 0 : (sg >= S_ ? S_ - 1 : sg);
    rows[r] = idx[b * S_ + sgc];
  }

  // --- gather: 2 batches of 6 rows; 12 uniform full-wave loads per batch,
  //     issue fenced from use by sched_barrier(0) (anti-sink). ---
  float ssr[12];
  #pragma unroll
  for (int h = 0; h < 2; ++h) {
    float4 va[6], vb[6];
    #pragma unroll
    for (int r = 0; r < 6; ++r) {
      const float* src = emb + (size_t)rows[h * 6 + r] * P_;
      va[r] = *(const float4*)(src + 4 * lane);        // f32 cols 4L..4L+3   (0..255)
      vb[r] = *(const float4*)(src + 44 + 4 * lane);   // f32 cols 44+4L..    (44..299)
    }
    __builtin_amdgcn_sched_barrier(0);  // loads stay clustered above converts
    #pragma unroll
    for (int r = 0; r < 6; ++r) {
      int ls = wu * 12 + h * 6 + r;
      int sg = s0 - 8 + ls;
      bool oob = (sg < 0) || (sg >= S_);
      float4 v = va[r], w = vb[r];
      if (oob) { v.x = v.y = v.z = v.w = 0.f; }
      // lanes >= 53 own f32 cols 256..299 via w; others' w is duplicate data
      bool tail = (lane >= 53);
      if (oob || !tail) { w.x = w.y = w.z = w.w = 0.f; }
      float ss = v.x * v.x + v.y * v.y + v.z * v.z + v.w * v.w +
                 w.x * w.x + w.y * w.y + w.z * w.z + w.w * w.w;
      unsigned u0 = cvtpk(v.x, v.y), u1 = cvtpk(v.z, v.w);
      *(uint2*)&xt[ls][4 * lane] = make_uint2(u0, u1);        // bf16 cols 4L..4L+3
      if (tail) {                                             // bf16 cols 256..299
        unsigned u2 = cvtpk(w.x, w.y), u3 = cvtpk(w.z, w.w);
        *(uint2*)&xt[ls][44 + 4 * lane] = make_uint2(u2, u3);
      } else if (lane < 5) {                                  // zero K-pad 300..319
        *(uint2*)&xt[ls][300 + 4 * lane] = make_uint2(0u, 0u);
      }
      ssr[h * 6 + r] = ss;
    }
  }
  #pragma unroll
  for (int r = 0; r < 12; ++r) {
    float ss = ssr[r];
    #pragma unroll
    for (int off = 32; off > 0; off >>= 1) ss += __shfl_xor(ss, off);
    if (lane == 0) scale_s[wu * 12 + r] = 1.f / (sqrtf(ss) + 0.001f);
  }
  __syncthreads();

  // --- dual GEMM: G over staged cols 0..48 (3 tiles), Y over central 32 (2).
  // A fragments loaded in-loop (L2-hot; no VGPR arrays -> no spill).
  float4v accG[3] = {};
  float4v accY[2] = {};
  int ml = lane & 15, quad = lane >> 4;
  const short8v* a1p = (const short8v*)(apack) + (size_t)((0 * 4 + wu) * 10) * 64 + lane;
  const short8v* a2p = (const short8v*)(apack) + (size_t)((1 * 4 + wu) * 10) * 64 + lane;
  #pragma unroll
  for (int ks = 0; ks < 10; ++ks) {
    short8v a1 = a1p[ks * 64];
    short8v a2 = a2p[ks * 64];
    int kk = ks * 32 + quad * 8;
    #pragma unroll
    for (int nt = 0; nt < 3; ++nt) {
      short8v bg = *(const short8v*)&xt[nt * 16 + ml][kk];
      accG[nt] = __builtin_amdgcn_mfma_f32_16x16x32_bf16(a1, bg, accG[nt], 0, 0, 0);
    }
    #pragma unroll
    for (int nt = 0; nt < 2; ++nt) {
      short8v by = *(const short8v*)&xt[8 + nt * 16 + ml][kk];
      accY[nt] = __builtin_amdgcn_mfma_f32_16x16x32_bf16(a2, by, accY[nt], 0, 0, 0);
    }
  }

  // --- Yt epilogue. C/D: col = lane&15 (s), row = quad*4+reg (m)
  #pragma unroll
  for (int nt = 0; nt < 2; ++nt) {
    int sg = s0 + nt * 16 + ml;
    #pragma unroll
    for (int reg = 0; reg < 4; ++reg) {
      int m = wu * 16 + quad * 4 + reg;
      if (m < K_) Yt[(size_t)(b * MPAD + m) * S_ + sg] = f2bf(accY[nt][reg]);
    }
  }

  // conv weights (uniform -> scalar loads)
  float wvv[11];
  #pragma unroll
  for (int t = 0; t < 11; ++t) wvv[t] = conv_w[t];
  float cb = conv_b[0];

  __syncthreads();  // all waves done reading xt -> safe to recycle as gst

  // --- scaled G tile -> LDS transposed: gst[scol][m] ---
  #pragma unroll
  for (int nt = 0; nt < 3; ++nt) {
    int scol = nt * 16 + ml;
    float sc = scale_s[scol];
    #pragma unroll
    for (int reg = 0; reg < 4; ++reg) {
      int m = wu * 16 + quad * 4 + reg;
      gst[scol][m] = accG[nt][reg] * sc;
    }
  }
  __syncthreads();

  // --- conv + relu + max over k. thread = (s = tid&31, k-group = tid>>5). ---
  // center s staged index = sl+8; taps at staged cols sl+3 .. sl+13 (max 44 < 48).
  int sl = tid & 31, kg = tid >> 5;
  float part = 0.f;  // relu >= 0, safe identity
  for (int k = kg; k < K_; k += 8) {
    float acc = cb;
    #pragma unroll
    for (int t = 0; t < 11; ++t) acc += wvv[t] * gst[sl + 3 + t][k];
    part = fmaxf(part, fmaxf(acc, 0.f));
  }
  mpart[kg][sl] = part;
  __syncthreads();
  if (tid < SCH) {
    float m0 = mpart[0][tid];
    #pragma unroll
    for (int i = 1; i < 8; ++i) m0 = fmaxf(m0, mpart[i][tid]);
    mbuf[b * S_ + s0 + tid] = m0;
  }
}

// ---------------------------------------------------------------------------
// K3: 4 blocks per b (grid 256, 512 threads). Each block recomputes the
// softmax over mbuf[b,:] (2 KB, cheap) and pools its k-subset of Yt.
// ---------------------------------------------------------------------------
__global__ __launch_bounds__(512) void k3_pool(const float* __restrict__ mbuf,
                                               const short* __restrict__ Yt,
                                               const float* __restrict__ b2,
                                               float* __restrict__ out) {
  __shared__ float beta[S_];
  __shared__ float red[8];
  int b = blockIdx.x >> 2, part = blockIdx.x & 3;
  int tid = threadIdx.x;
  int lane = tid & 63, wv = tid >> 6;

  float mx = mbuf[b * S_ + tid];

  // block softmax over s (512 threads)
  float r = mx;
  #pragma unroll
  for (int off = 32; off > 0; off >>= 1) r = fmaxf(r, __shfl_xor(r, off));
  if (lane == 0) red[wv] = r;
  __syncthreads();
  float bm = red[0];
  #pragma unroll
  for (int i = 1; i < 8; ++i) bm = fmaxf(bm, red[i]);
  float e = __expf(mx - bm);
  r = e;
  #pragma unroll
  for (int off = 32; off > 0; off >>= 1) r += __shfl_xor(r, off);
  __syncthreads();               // everyone done reading red (max) before rewrite
  if (lane == 0) red[wv] = r;
  __syncthreads();
  float sum = 0.f;
  #pragma unroll
  for (int i = 0; i < 8; ++i) sum += red[i];
  beta[tid] = e / (sum * (float)S_);   // fold 1/S of jnp.mean into beta
  __syncthreads();

  // out[b,k] = sum_s beta[s]*Yt[b,k,s] + b2[k]; this block covers k≡part (mod 4)
  const float4* bp = (const float4*)&beta[lane * 8];
  float4 b0 = bp[0], b1 = bp[1];
  for (int k = part + 4 * wv; k < K_; k += 32) {
    short8v y = *(const short8v*)(Yt + (((size_t)(b * MPAD + k)) << 9) + lane * 8);
    float acc = b0.x * bf2f(y[0]) + b0.y * bf2f(y[1]) +
                b0.z * bf2f(y[2]) + b0.w * bf2f(y[3]) +
                b1.x * bf2f(y[4]) + b1.y * bf2f(y[5]) +
                b1.z * bf2f(y[6]) + b1.w * bf2f(y[7]);
    #pragma unroll
    for (int off = 32; off > 0; off >>= 1) acc += __shfl_xor(acc, off);
    if (lane == 0) out[b * K_ + k] = acc + b2[k];
  }
}

// ---------------------------------------------------------------------------
extern "C" void kernel_launch(void* const* d_in, const int* in_sizes, int n_in,
                              void* d_out, int out_size, void* d_ws, size_t ws_size,
                              hipStream_t stream) {
  const int*   idx    = (const int*)  d_in[0];
  const float* emb    = (const float*)d_in[1];
  const float* C      = (const float*)d_in[2];
  const float* conv_w = (const float*)d_in[3];
  const float* conv_b = (const float*)d_in[4];
  const float* W2     = (const float*)d_in[5];
  const float* b2     = (const float*)d_in[6];
  float* out = (float*)d_out;

  char* ws = (char*)d_ws;
  // ws layout (bytes): apack 81920 | Yt bf16 4 MiB | mbuf f32 128 KiB
  short* apack = (short*)(ws);
  short* Yt    = (short*)(ws + 81920);
  float* mbuf  = (float*)(ws + 81920 + 4194304);

  hipLaunchKernelGGL(k1_prep, dim3(80),   dim3(64),  0, stream, C, W2, apack);
  hipLaunchKernelGGL(k2_gemm, dim3(1024), dim3(256), 0, stream,
                     idx, emb, apack, Yt, conv_w, conv_b, mbuf);
  hipLaunchKernelGGL(k3_pool, dim3(256),  dim3(512), 0, stream, mbuf, Yt, b2, out);
}